// Round 2
// baseline (3494.236 us; speedup 1.0000x reference)
//
#include <hip/hip_runtime.h>
#include <cstdint>

#define NE 8
#define NEX 9
#define NTOK 16384
#define DDIM 1024
#define HDIM 2816

typedef unsigned short u16;
typedef __attribute__((ext_vector_type(8))) short short8;
typedef __attribute__((ext_vector_type(4))) float f32x4;

__device__ __forceinline__ u16 f2bf(float f) {
  uint32_t u = __builtin_bit_cast(uint32_t, f);
  u += 0x7FFFu + ((u >> 16) & 1u);
  return (u16)(u >> 16);
}

__device__ __forceinline__ float wave_reduce_sum(float v) {
  for (int off = 32; off > 0; off >>= 1) v += __shfl_xor(v, off, 64);
  return v;
}

// ---------------- init ----------------
__global__ void init_kernel(int* cnt, float* Pacc, float* fcnt) {
  int t = threadIdx.x;
  if (t < NEX) cnt[t] = (t == 8) ? NTOK : 0;
  if (t < NE) { Pacc[t] = 0.f; fcnt[t] = 0.f; }
}

// ---------------- fp32 -> bf16 convert ----------------
struct CvtArgs {
  const float* src[7];
  u16* dst[7];
  long long cum[8];  // cumulative float4-group counts
};

__global__ void convert_kernel(CvtArgs a) {
  long long stride = (long long)gridDim.x * blockDim.x;
  long long total = a.cum[7];
  for (long long g = (long long)blockIdx.x * blockDim.x + threadIdx.x; g < total; g += stride) {
    int s = 0;
    while (g >= a.cum[s + 1]) s++;
    long long off = (g - a.cum[s]) * 4;
    float4 v = *reinterpret_cast<const float4*>(a.src[s] + off);
    union { u16 u[4]; uint2 w; } o;
    o.u[0] = f2bf(v.x); o.u[1] = f2bf(v.y); o.u[2] = f2bf(v.z); o.u[3] = f2bf(v.w);
    *reinterpret_cast<uint2*>(a.dst[s] + off) = o.w;
  }
}

// ---------------- router (fp32 logits to match reference top-k) ----------------
__global__ __launch_bounds__(256) void router_kernel(
    const float* __restrict__ x, const float* __restrict__ gw,
    int* __restrict__ tok, float* __restrict__ wtl,
    int* __restrict__ cnt, float* __restrict__ Pacc, float* __restrict__ fcnt) {
  int lane = threadIdx.x & 63;
  int wv = threadIdx.x >> 6;
  __shared__ float red[4][16];
  float pP[NE], pF[NE];
#pragma unroll
  for (int e = 0; e < NE; e++) { pP[e] = 0.f; pF[e] = 0.f; }
  int t0 = blockIdx.x * 16 + wv * 4;
  for (int ti = 0; ti < 4; ti++) {
    int t = t0 + ti;
    float part[NE];
#pragma unroll
    for (int e = 0; e < NE; e++) part[e] = 0.f;
    const float* xp = x + (size_t)t * DDIM;
#pragma unroll
    for (int j = 0; j < 16; j++) {
      float xv = xp[lane + j * 64];
#pragma unroll
      for (int e = 0; e < NE; e++) part[e] += xv * gw[e * DDIM + lane + j * 64];
    }
#pragma unroll
    for (int e = 0; e < NE; e++) part[e] = wave_reduce_sum(part[e]);
    if (lane == 0) {
      float v0 = -1e30f, v1 = -1e30f; int i0 = 0, i1 = 0;
#pragma unroll
      for (int e = 0; e < NE; e++) {
        float v = part[e];
        if (v > v0) { v1 = v0; i1 = i0; v0 = v; i0 = e; }
        else if (v > v1) { v1 = v; i1 = e; }
      }
      float e1 = expf(v1 - v0);
      float w0 = 1.f / (1.f + e1);
      float w1 = e1 * w0;
      float s = 0.f, g[NE];
#pragma unroll
      for (int e = 0; e < NE; e++) { g[e] = expf(part[e] - v0); s += g[e]; }
      float inv = 1.f / s;
#pragma unroll
      for (int e = 0; e < NE; e++) pP[e] += g[e] * inv;
      pF[i0] += 1.f;
      int p0 = atomicAdd(&cnt[i0], 1);
      tok[i0 * NTOK + p0] = t; wtl[i0 * NTOK + p0] = w0;
      int p1 = atomicAdd(&cnt[i1], 1);
      tok[i1 * NTOK + p1] = t; wtl[i1 * NTOK + p1] = w1;
      tok[8 * NTOK + t] = t; wtl[8 * NTOK + t] = 1.f;
    }
  }
  if (lane == 0) {
#pragma unroll
    for (int e = 0; e < NE; e++) { red[wv][e] = pP[e]; red[wv][e + 8] = pF[e]; }
  }
  __syncthreads();
  if (threadIdx.x < 16) {
    float s = red[0][threadIdx.x] + red[1][threadIdx.x] + red[2][threadIdx.x] + red[3][threadIdx.x];
    if (threadIdx.x < 8) atomicAdd(&Pacc[threadIdx.x], s);
    else atomicAdd(&fcnt[threadIdx.x - 8], s);
  }
}

// ---------------- finalize router: offsets + aux loss ----------------
__global__ void finalize_router(const int* cnt, int* offs, const float* Pacc,
                                const float* fcnt, float* out_aux, int batched) {
  if (threadIdx.x == 0 && blockIdx.x == 0) {
    int p = NTOK;
    for (int e = 0; e < NE; e++) { offs[e] = batched ? p : 0; p += cnt[e]; }
    offs[8] = 0;
    float aux = 0.f;
    for (int e = 0; e < NE; e++)
      aux += (fcnt[e] * (1.f / NTOK)) * (Pacc[e] * (1.f / NTOK));
    *out_aux = 0.01f * 8.f * aux;
  }
}

// ---------------- pass 1: A = gelu(X Wg^T) * (X Wu^T), bf16 out ----------------
// WB = weights pre-converted to bf16 (global_load_lds); else fp32 reg-staged.
template<bool WB>
__global__ __launch_bounds__(256, 2) void pass1_kernel(
    const u16* __restrict__ xbf, const void* __restrict__ WGall,
    const void* __restrict__ WUall, const void* __restrict__ SG,
    const void* __restrict__ SU, const int* __restrict__ tok,
    const int* __restrict__ cnt, const int* __restrict__ offs,
    u16* __restrict__ Abuf, int e0) {
  int e = e0 + blockIdx.z;
  int mt = blockIdx.y;
  int nt = blockIdx.x;
  int Me = cnt[e];
  if (mt * 128 >= Me) return;
  int base = offs[e];

  __shared__ u16 lX[128 * 64];
  __shared__ u16 lG[128 * 64];
  __shared__ u16 lU[128 * 64];

  int tid = threadIdx.x, lane = tid & 63, wv = tid >> 6;
  int wr = wv >> 1, wc = wv & 1;
  size_t wst = (size_t)HDIM * DDIM;

  // X staging sources (gathered token rows, bf16, via global_load_lds)
  const u16* gx[4];
#pragma unroll
  for (int q = 0; q < 4; q++) {
    int r = (wv * 4 + q) * 8 + (lane >> 3);
    int gm = mt * 128 + r;
    int tk = (gm < Me) ? tok[e * NTOK + gm] : 0;
    gx[q] = xbf + (size_t)tk * DDIM + (lane & 7) * 8;
  }

  const u16 *gg[4], *gu[4];
  const float *pg0 = nullptr, *pu0 = nullptr;
  u16 *lgw = nullptr, *luw = nullptr;
  if constexpr (WB) {
    const u16* G = (e == 8) ? (const u16*)SG : (const u16*)WGall + (size_t)e * wst;
    const u16* U = (e == 8) ? (const u16*)SU : (const u16*)WUall + (size_t)e * wst;
#pragma unroll
    for (int q = 0; q < 4; q++) {
      int r = (wv * 4 + q) * 8 + (lane >> 3);
      gg[q] = G + (size_t)(nt * 128 + r) * DDIM + (lane & 7) * 8;
      gu[q] = U + (size_t)(nt * 128 + r) * DDIM + (lane & 7) * 8;
    }
  } else {
    const float* G = (e == 8) ? (const float*)SG : (const float*)WGall + (size_t)e * wst;
    const float* U = (e == 8) ? (const float*)SU : (const float*)WUall + (size_t)e * wst;
    int r0 = wv * 32 + (lane >> 4);
    int c0 = (lane & 15) * 4;
    pg0 = G + (size_t)(nt * 128 + r0) * DDIM + c0;
    pu0 = U + (size_t)(nt * 128 + r0) * DDIM + c0;
    lgw = lG + r0 * 64 + c0;
    luw = lU + r0 * 64 + c0;
  }

  f32x4 accG[4][4] = {};
  f32x4 accU[4][4] = {};

  for (int kt = 0; kt < DDIM / 64; kt++) {
    __syncthreads();
    int ko = kt * 64;
#pragma unroll
    for (int q = 0; q < 4; q++) {
      int ldsoff = (wv * 4 + q) * 512;
      __builtin_amdgcn_global_load_lds(
          (const __attribute__((address_space(1))) unsigned int*)(gx[q] + ko),
          (__attribute__((address_space(3))) unsigned int*)(lX + ldsoff), 16, 0, 0);
      if constexpr (WB) {
        __builtin_amdgcn_global_load_lds(
            (const __attribute__((address_space(1))) unsigned int*)(gg[q] + ko),
            (__attribute__((address_space(3))) unsigned int*)(lG + ldsoff), 16, 0, 0);
        __builtin_amdgcn_global_load_lds(
            (const __attribute__((address_space(1))) unsigned int*)(gu[q] + ko),
            (__attribute__((address_space(3))) unsigned int*)(lU + ldsoff), 16, 0, 0);
      }
    }
    if constexpr (!WB) {
#pragma unroll
      for (int q = 0; q < 8; q++) {
        float4 vg = *reinterpret_cast<const float4*>(pg0 + ko + q * 4 * DDIM);
        float4 vu = *reinterpret_cast<const float4*>(pu0 + ko + q * 4 * DDIM);
        union { u16 h[4]; uint2 w; } og, ou;
        og.h[0] = f2bf(vg.x); og.h[1] = f2bf(vg.y); og.h[2] = f2bf(vg.z); og.h[3] = f2bf(vg.w);
        ou.h[0] = f2bf(vu.x); ou.h[1] = f2bf(vu.y); ou.h[2] = f2bf(vu.z); ou.h[3] = f2bf(vu.w);
        *reinterpret_cast<uint2*>(lgw + q * 256) = og.w;
        *reinterpret_cast<uint2*>(luw + q * 256) = ou.w;
      }
    }
    asm volatile("s_waitcnt vmcnt(0)" ::: "memory");
    __syncthreads();

#pragma unroll
    for (int kk = 0; kk < 2; kk++) {
      int kb = kk * 32 + ((lane >> 4) * 8);
      short8 af[4];
#pragma unroll
      for (int m = 0; m < 4; m++) {
        int row = wr * 64 + m * 16 + (lane & 15);
        af[m] = *reinterpret_cast<const short8*>(lX + row * 64 + kb);
      }
#pragma unroll
      for (int n = 0; n < 4; n++) {
        int hr = wc * 64 + n * 16 + (lane & 15);
        short8 bg = *reinterpret_cast<const short8*>(lG + hr * 64 + kb);
        short8 bu = *reinterpret_cast<const short8*>(lU + hr * 64 + kb);
#pragma unroll
        for (int m = 0; m < 4; m++) {
          accG[m][n] = __builtin_amdgcn_mfma_f32_16x16x32_bf16(af[m], bg, accG[m][n], 0, 0, 0);
          accU[m][n] = __builtin_amdgcn_mfma_f32_16x16x32_bf16(af[m], bu, accU[m][n], 0, 0, 0);
        }
      }
    }
  }

  int rsub = (lane >> 4) * 4, csub = lane & 15;
#pragma unroll
  for (int m = 0; m < 4; m++) {
#pragma unroll
    for (int i = 0; i < 4; i++) {
      int row = wr * 64 + m * 16 + rsub + i;
      int gm = mt * 128 + row;
      if (gm < Me) {
        size_t rb = (size_t)(base + gm) * HDIM + nt * 128;
#pragma unroll
        for (int n = 0; n < 4; n++) {
          float hg = accG[m][n][i];
          float hu = accU[m][n][i];
          float a = 0.5f * hg * (1.f + erff(hg * 0.70710678118f)) * hu;
          Abuf[rb + wc * 64 + n * 16 + csub] = f2bf(a);
        }
      }
    }
  }
}

// ---------------- pass 2: Y = A Wd^T, scatter to out ----------------
template<bool WB>
__global__ __launch_bounds__(256, 2) void pass2_kernel(
    const u16* __restrict__ Abuf, const void* __restrict__ WDall,
    const void* __restrict__ SD, const int* __restrict__ tok,
    const float* __restrict__ wtl, const int* __restrict__ cnt,
    const int* __restrict__ offs, float* __restrict__ out, int e0, int mode) {
  int e = e0 + blockIdx.z;
  int mt = blockIdx.y;
  int nt = blockIdx.x;
  int Me = cnt[e];
  if (mt * 128 >= Me) return;
  int base = offs[e];
  size_t wst = (size_t)HDIM * DDIM;

  __shared__ u16 lA[128 * 64];
  __shared__ u16 lB[128 * 64];

  int tid = threadIdx.x, lane = tid & 63, wv = tid >> 6;
  int wr = wv >> 1, wc = wv & 1;

  const u16* ga[4];
#pragma unroll
  for (int q = 0; q < 4; q++) {
    int r = (wv * 4 + q) * 8 + (lane >> 3);
    int slot = base + mt * 128 + r;  // overrun rows only feed unwritten output rows
    ga[q] = Abuf + (size_t)slot * HDIM + (lane & 7) * 8;
  }

  const u16* gb[4];
  const float* pd0 = nullptr;
  u16* lbw = nullptr;
  if constexpr (WB) {
    const u16* D = (e == 8) ? (const u16*)SD : (const u16*)WDall + (size_t)e * wst;
#pragma unroll
    for (int q = 0; q < 4; q++) {
      int r = (wv * 4 + q) * 8 + (lane >> 3);
      gb[q] = D + (size_t)(nt * 128 + r) * HDIM + (lane & 7) * 8;
    }
  } else {
    const float* D = (e == 8) ? (const float*)SD : (const float*)WDall + (size_t)e * wst;
    int r0 = wv * 32 + (lane >> 4);
    int c0 = (lane & 15) * 4;
    pd0 = D + (size_t)(nt * 128 + r0) * HDIM + c0;
    lbw = lB + r0 * 64 + c0;
  }

  f32x4 acc[4][4] = {};

  for (int kt = 0; kt < HDIM / 64; kt++) {
    __syncthreads();
    int ko = kt * 64;
#pragma unroll
    for (int q = 0; q < 4; q++) {
      int ldsoff = (wv * 4 + q) * 512;
      __builtin_amdgcn_global_load_lds(
          (const __attribute__((address_space(1))) unsigned int*)(ga[q] + ko),
          (__attribute__((address_space(3))) unsigned int*)(lA + ldsoff), 16, 0, 0);
      if constexpr (WB) {
        __builtin_amdgcn_global_load_lds(
            (const __attribute__((address_space(1))) unsigned int*)(gb[q] + ko),
            (__attribute__((address_space(3))) unsigned int*)(lB + ldsoff), 16, 0, 0);
      }
    }
    if constexpr (!WB) {
#pragma unroll
      for (int q = 0; q < 8; q++) {
        float4 vd = *reinterpret_cast<const float4*>(pd0 + ko + q * 4 * HDIM);
        union { u16 h[4]; uint2 w; } od;
        od.h[0] = f2bf(vd.x); od.h[1] = f2bf(vd.y); od.h[2] = f2bf(vd.z); od.h[3] = f2bf(vd.w);
        *reinterpret_cast<uint2*>(lbw + q * 256) = od.w;
      }
    }
    asm volatile("s_waitcnt vmcnt(0)" ::: "memory");
    __syncthreads();

#pragma unroll
    for (int kk = 0; kk < 2; kk++) {
      int kb = kk * 32 + ((lane >> 4) * 8);
      short8 af[4];
#pragma unroll
      for (int m = 0; m < 4; m++) {
        int row = wr * 64 + m * 16 + (lane & 15);
        af[m] = *reinterpret_cast<const short8*>(lA + row * 64 + kb);
      }
#pragma unroll
      for (int n = 0; n < 4; n++) {
        int dr = wc * 64 + n * 16 + (lane & 15);
        short8 bd = *reinterpret_cast<const short8*>(lB + dr * 64 + kb);
#pragma unroll
        for (int m = 0; m < 4; m++) {
          acc[m][n] = __builtin_amdgcn_mfma_f32_16x16x32_bf16(af[m], bd, acc[m][n], 0, 0, 0);
        }
      }
    }
  }

  int rsub = (lane >> 4) * 4, csub = lane & 15;
#pragma unroll
  for (int m = 0; m < 4; m++) {
#pragma unroll
    for (int i = 0; i < 4; i++) {
      int row = wr * 64 + m * 16 + rsub + i;
      int gm = mt * 128 + row;
      if (gm < Me) {
        int t = tok[e * NTOK + gm];
        float w = mode ? wtl[e * NTOK + gm] : 1.f;
        size_t ob = (size_t)t * DDIM + nt * 128;
#pragma unroll
        for (int n = 0; n < 4; n++) {
          float v = w * acc[m][n][i];
          int c = wc * 64 + n * 16 + csub;
          if (mode) atomicAdd(&out[ob + c], v);
          else out[ob + c] = v;
        }
      }
    }
  }
}

// ---------------- host launcher ----------------
extern "C" void kernel_launch(void* const* d_in, const int* in_sizes, int n_in,
                              void* d_out, int out_size, void* d_ws, size_t ws_size,
                              hipStream_t stream) {
  const float* x  = (const float*)d_in[0];
  const float* gw = (const float*)d_in[1];
  const float* wg = (const float*)d_in[2];
  const float* wu = (const float*)d_in[3];
  const float* wd = (const float*)d_in[4];
  const float* sg = (const float*)d_in[5];
  const float* su = (const float*)d_in[6];
  const float* sd = (const float*)d_in[7];
  float* out = (float*)d_out;

  // Footprint tiers (bytes):
  //   A: x + bf16 weights + batched Abuf ~ 468.0 MB
  //   B: x + batched Abuf               ~ 312.3 MB
  //   C: x + per-expert Abuf            ~ 127.8 MB
  bool tierA = ws_size >= 470000000ULL;
  bool tierB = !tierA && ws_size >= 315000000ULL;
  bool batched = tierA || tierB;
  bool wcvt = tierA;

  char* ws = (char*)d_ws;
  size_t o = 0;
  auto alloc = [&](size_t bytes) -> void* {
    void* p = ws + o;
    o = (o + bytes + 255) & ~(size_t)255;
    return p;
  };
  u16* xbf = (u16*)alloc((size_t)NTOK * DDIM * 2);
  u16 *wgbf = nullptr, *wubf = nullptr, *wdbf = nullptr;
  u16 *sgbf = nullptr, *subf = nullptr, *sdbf = nullptr;
  if (wcvt) {
    wgbf = (u16*)alloc((size_t)NE * HDIM * DDIM * 2);
    wubf = (u16*)alloc((size_t)NE * HDIM * DDIM * 2);
    wdbf = (u16*)alloc((size_t)NE * DDIM * HDIM * 2);
    sgbf = (u16*)alloc((size_t)HDIM * DDIM * 2);
    subf = (u16*)alloc((size_t)HDIM * DDIM * 2);
    sdbf = (u16*)alloc((size_t)DDIM * HDIM * 2);
  }
  size_t abuf_rows = batched ? ((size_t)3 * NTOK + 128) : ((size_t)NTOK + 128);
  u16* Abuf = (u16*)alloc(abuf_rows * HDIM * 2);
  int*   tok  = (int*)alloc((size_t)NEX * NTOK * 4);
  float* wtl  = (float*)alloc((size_t)NEX * NTOK * 4);
  int*   cnt  = (int*)alloc(64);
  int*   offs = (int*)alloc(64);
  float* Pacc = (float*)alloc(64);
  float* fcnt = (float*)alloc(64);

  init_kernel<<<1, 64, 0, stream>>>(cnt, Pacc, fcnt);

  CvtArgs ca;
  long long sizes4[7];
  int nsrc;
  ca.src[0] = x; ca.dst[0] = xbf;
  sizes4[0] = (long long)NTOK * DDIM / 4;
  if (wcvt) {
    ca.src[1] = wg; ca.dst[1] = wgbf; sizes4[1] = (long long)NE * HDIM * DDIM / 4;
    ca.src[2] = wu; ca.dst[2] = wubf; sizes4[2] = (long long)NE * HDIM * DDIM / 4;
    ca.src[3] = wd; ca.dst[3] = wdbf; sizes4[3] = (long long)NE * DDIM * HDIM / 4;
    ca.src[4] = sg; ca.dst[4] = sgbf; sizes4[4] = (long long)HDIM * DDIM / 4;
    ca.src[5] = su; ca.dst[5] = subf; sizes4[5] = (long long)HDIM * DDIM / 4;
    ca.src[6] = sd; ca.dst[6] = sdbf; sizes4[6] = (long long)DDIM * HDIM / 4;
    nsrc = 7;
  } else {
    nsrc = 1;
  }
  ca.cum[0] = 0;
  for (int i = 0; i < 7; i++)
    ca.cum[i + 1] = ca.cum[i] + (i < nsrc ? sizes4[i] : 0);
  convert_kernel<<<4096, 256, 0, stream>>>(ca);

  router_kernel<<<NTOK / 16, 256, 0, stream>>>(x, gw, tok, wtl, cnt, Pacc, fcnt);
  finalize_router<<<1, 64, 0, stream>>>(cnt, offs, Pacc, fcnt,
                                        out + (out_size - 1), batched ? 1 : 0);

  const void *WG, *WU, *WD, *SG, *SU, *SD;
  if (wcvt) { WG = wgbf; WU = wubf; WD = wdbf; SG = sgbf; SU = subf; SD = sdbf; }
  else      { WG = wg;   WU = wu;   WD = wd;   SG = sg;   SU = su;   SD = sd;  }

  if (batched) {
    if (wcvt) {
      pass1_kernel<true><<<dim3(HDIM / 128, NTOK / 128, NEX), 256, 0, stream>>>(
          xbf, WG, WU, SG, SU, tok, cnt, offs, Abuf, 0);
      pass2_kernel<true><<<dim3(DDIM / 128, NTOK / 128, 1), 256, 0, stream>>>(
          Abuf, WD, SD, tok, wtl, cnt, offs, out, 8, 0);
      pass2_kernel<true><<<dim3(DDIM / 128, NTOK / 128, NE), 256, 0, stream>>>(
          Abuf, WD, SD, tok, wtl, cnt, offs, out, 0, 1);
    } else {
      pass1_kernel<false><<<dim3(HDIM / 128, NTOK / 128, NEX), 256, 0, stream>>>(
          xbf, WG, WU, SG, SU, tok, cnt, offs, Abuf, 0);
      pass2_kernel<false><<<dim3(DDIM / 128, NTOK / 128, 1), 256, 0, stream>>>(
          Abuf, WD, SD, tok, wtl, cnt, offs, out, 8, 0);
      pass2_kernel<false><<<dim3(DDIM / 128, NTOK / 128, NE), 256, 0, stream>>>(
          Abuf, WD, SD, tok, wtl, cnt, offs, out, 0, 1);
    }
  } else {
    // serial per-expert: shared expert (store) first, then routed (atomicAdd)
    for (int k = 0; k < NEX; k++) {
      int e = (k == 0) ? 8 : (k - 1);
      pass1_kernel<false><<<dim3(HDIM / 128, NTOK / 128, 1), 256, 0, stream>>>(
          xbf, WG, WU, SG, SU, tok, cnt, offs, Abuf, e);
      pass2_kernel<false><<<dim3(DDIM / 128, NTOK / 128, 1), 256, 0, stream>>>(
          Abuf, WD, SD, tok, wtl, cnt, offs, out, e, (e == 8) ? 0 : 1);
    }
  }
}

// Round 3
// 3355.705 us; speedup vs baseline: 1.0413x; 1.0413x over previous
//
#include <hip/hip_runtime.h>
#include <cstdint>

#define NE 8
#define NEX 9
#define NTOK 16384
#define DDIM 1024
#define HDIM 2816

typedef unsigned short u16;
typedef __attribute__((ext_vector_type(8))) short short8;
typedef __attribute__((ext_vector_type(4))) float f32x4;

__device__ __forceinline__ u16 f2bf(float f) {
  uint32_t u = __builtin_bit_cast(uint32_t, f);
  u += 0x7FFFu + ((u >> 16) & 1u);
  return (u16)(u >> 16);
}

__device__ __forceinline__ float wave_reduce_sum(float v) {
  for (int off = 32; off > 0; off >>= 1) v += __shfl_xor(v, off, 64);
  return v;
}

// ---------------- init ----------------
__global__ void init_kernel(int* cnt, float* Pacc, float* fcnt) {
  int t = threadIdx.x;
  if (t < NEX) cnt[t] = (t == 8) ? NTOK : 0;
  if (t < NE) { Pacc[t] = 0.f; fcnt[t] = 0.f; }
}

// ---------------- fp32 -> bf16 convert ----------------
struct CvtArgs {
  const float* src[7];
  u16* dst[7];
  long long cum[8];  // cumulative float4-group counts
};

__global__ void convert_kernel(CvtArgs a) {
  long long stride = (long long)gridDim.x * blockDim.x;
  long long total = a.cum[7];
  for (long long g = (long long)blockIdx.x * blockDim.x + threadIdx.x; g < total; g += stride) {
    int s = 0;
    while (g >= a.cum[s + 1]) s++;
    long long off = (g - a.cum[s]) * 4;
    float4 v = *reinterpret_cast<const float4*>(a.src[s] + off);
    union { u16 u[4]; uint2 w; } o;
    o.u[0] = f2bf(v.x); o.u[1] = f2bf(v.y); o.u[2] = f2bf(v.z); o.u[3] = f2bf(v.w);
    *reinterpret_cast<uint2*>(a.dst[s] + off) = o.w;
  }
}

// ---------------- router (fp32 logits to match reference top-k) ----------------
__global__ __launch_bounds__(256) void router_kernel(
    const float* __restrict__ x, const float* __restrict__ gw,
    int* __restrict__ tok, float* __restrict__ wtl,
    int* __restrict__ cnt, float* __restrict__ Pacc, float* __restrict__ fcnt) {
  int lane = threadIdx.x & 63;
  int wv = threadIdx.x >> 6;
  __shared__ float red[4][16];
  float pP[NE], pF[NE];
#pragma unroll
  for (int e = 0; e < NE; e++) { pP[e] = 0.f; pF[e] = 0.f; }
  int t0 = blockIdx.x * 16 + wv * 4;
  for (int ti = 0; ti < 4; ti++) {
    int t = t0 + ti;
    float part[NE];
#pragma unroll
    for (int e = 0; e < NE; e++) part[e] = 0.f;
    const float* xp = x + (size_t)t * DDIM;
#pragma unroll
    for (int j = 0; j < 16; j++) {
      float xv = xp[lane + j * 64];
#pragma unroll
      for (int e = 0; e < NE; e++) part[e] += xv * gw[e * DDIM + lane + j * 64];
    }
#pragma unroll
    for (int e = 0; e < NE; e++) part[e] = wave_reduce_sum(part[e]);
    if (lane == 0) {
      float v0 = -1e30f, v1 = -1e30f; int i0 = 0, i1 = 0;
#pragma unroll
      for (int e = 0; e < NE; e++) {
        float v = part[e];
        if (v > v0) { v1 = v0; i1 = i0; v0 = v; i0 = e; }
        else if (v > v1) { v1 = v; i1 = e; }
      }
      float e1 = expf(v1 - v0);
      float w0 = 1.f / (1.f + e1);
      float w1 = e1 * w0;
      float s = 0.f, g[NE];
#pragma unroll
      for (int e = 0; e < NE; e++) { g[e] = expf(part[e] - v0); s += g[e]; }
      float inv = 1.f / s;
#pragma unroll
      for (int e = 0; e < NE; e++) pP[e] += g[e] * inv;
      pF[i0] += 1.f;
      int p0 = atomicAdd(&cnt[i0], 1);
      tok[i0 * NTOK + p0] = t; wtl[i0 * NTOK + p0] = w0;
      int p1 = atomicAdd(&cnt[i1], 1);
      tok[i1 * NTOK + p1] = t; wtl[i1 * NTOK + p1] = w1;
      tok[8 * NTOK + t] = t; wtl[8 * NTOK + t] = 1.f;
    }
  }
  if (lane == 0) {
#pragma unroll
    for (int e = 0; e < NE; e++) { red[wv][e] = pP[e]; red[wv][e + 8] = pF[e]; }
  }
  __syncthreads();
  if (threadIdx.x < 16) {
    float s = red[0][threadIdx.x] + red[1][threadIdx.x] + red[2][threadIdx.x] + red[3][threadIdx.x];
    if (threadIdx.x < 8) atomicAdd(&Pacc[threadIdx.x], s);
    else atomicAdd(&fcnt[threadIdx.x - 8], s);
  }
}

// ---------------- finalize router: offsets + aux loss ----------------
__global__ void finalize_router(const int* cnt, int* offs, const float* Pacc,
                                const float* fcnt, float* out_aux, int batched) {
  if (threadIdx.x == 0 && blockIdx.x == 0) {
    int p = NTOK;
    for (int e = 0; e < NE; e++) { offs[e] = batched ? p : 0; p += cnt[e]; }
    offs[8] = 0;
    float aux = 0.f;
    for (int e = 0; e < NE; e++)
      aux += (fcnt[e] * (1.f / NTOK)) * (Pacc[e] * (1.f / NTOK));
    *out_aux = 0.01f * 8.f * aux;
  }
}

// LDS XOR swizzle convention (tile = [128 rows][8 chunks of 8 u16]):
//   physical_chunk = logical_chunk ^ (row & 7)
// Staging lane l writes phys chunk (l&7) of row with row&7 == (l>>3)
//   -> source must fetch logical chunk (l&7)^(l>>3).
// Fragment reads need logical chunk kk*4+(lane>>4) of a row with row&7 == lane&7
//   -> read phys chunk (kk*4+(lane>>4))^(lane&7).

// ---------------- pass 1: A = gelu(X Wg^T) * (X Wu^T), bf16 out ----------------
// X fragments are read directly from global (L1/L2-resident working set);
// only the two weight tiles are staged in LDS (swizzled).
template<bool WB>
__global__ __launch_bounds__(256, 2) void pass1_kernel(
    const u16* __restrict__ xbf, const void* __restrict__ WGall,
    const void* __restrict__ WUall, const void* __restrict__ SG,
    const void* __restrict__ SU, const int* __restrict__ tok,
    const int* __restrict__ cnt, const int* __restrict__ offs,
    u16* __restrict__ Abuf, int e0) {
  int e = e0 + blockIdx.z;
  int mt = blockIdx.y;
  int nt = blockIdx.x;
  int Me = cnt[e];
  if (mt * 128 >= Me) return;
  int base = offs[e];

  __shared__ u16 lG[128 * 64];
  __shared__ u16 lU[128 * 64];

  int tid = threadIdx.x, lane = tid & 63, wv = tid >> 6;
  int wr = wv >> 1, wc = wv & 1;
  size_t wst = (size_t)HDIM * DDIM;

  // A-row (token) pointers: 4 gathered rows per lane, read direct from global.
  const u16* pa[4];
#pragma unroll
  for (int m = 0; m < 4; m++) {
    int gm = mt * 128 + wr * 64 + m * 16 + (lane & 15);
    int tk = (gm < Me) ? tok[e * NTOK + gm] : 0;
    pa[m] = xbf + (size_t)tk * DDIM + (lane >> 4) * 8;
  }

  int swsrc = ((lane & 7) ^ (lane >> 3)) * 8;  // swizzled source chunk (u16 units)

  const u16 *gg[4], *gu[4];
  const float *pg0 = nullptr, *pu0 = nullptr;
  if constexpr (WB) {
    const u16* G = (e == 8) ? (const u16*)SG : (const u16*)WGall + (size_t)e * wst;
    const u16* U = (e == 8) ? (const u16*)SU : (const u16*)WUall + (size_t)e * wst;
#pragma unroll
    for (int q = 0; q < 4; q++) {
      int r = (wv * 4 + q) * 8 + (lane >> 3);
      gg[q] = G + (size_t)(nt * 128 + r) * DDIM + swsrc;
      gu[q] = U + (size_t)(nt * 128 + r) * DDIM + swsrc;
    }
  } else {
    const float* G = (e == 8) ? (const float*)SG : (const float*)WGall + (size_t)e * wst;
    const float* U = (e == 8) ? (const float*)SU : (const float*)WUall + (size_t)e * wst;
    int r0 = wv * 32 + (lane >> 4);
    int c0 = (lane & 15) * 4;
    pg0 = G + (size_t)(nt * 128 + r0) * DDIM + c0;
    pu0 = U + (size_t)(nt * 128 + r0) * DDIM + c0;
  }

  f32x4 accG[4][4] = {};
  f32x4 accU[4][4] = {};

  for (int kt = 0; kt < DDIM / 64; kt++) {
    __syncthreads();
    int ko = kt * 64;
    if constexpr (WB) {
#pragma unroll
      for (int q = 0; q < 4; q++) {
        int ldsoff = (wv * 4 + q) * 512;
        __builtin_amdgcn_global_load_lds(
            (const __attribute__((address_space(1))) unsigned int*)(gg[q] + ko),
            (__attribute__((address_space(3))) unsigned int*)(lG + ldsoff), 16, 0, 0);
        __builtin_amdgcn_global_load_lds(
            (const __attribute__((address_space(1))) unsigned int*)(gu[q] + ko),
            (__attribute__((address_space(3))) unsigned int*)(lU + ldsoff), 16, 0, 0);
      }
    } else {
      int r0 = wv * 32 + (lane >> 4);
      int c0 = (lane & 15) * 4;
      int chunk = c0 >> 3, win = c0 & 7;
#pragma unroll
      for (int q = 0; q < 8; q++) {
        int row = r0 + q * 4;
        int pc = (((chunk ^ (row & 7)) << 3) | win);
        float4 vg = *reinterpret_cast<const float4*>(pg0 + ko + q * 4 * DDIM);
        float4 vu = *reinterpret_cast<const float4*>(pu0 + ko + q * 4 * DDIM);
        union { u16 h[4]; uint2 w; } og, ou;
        og.h[0] = f2bf(vg.x); og.h[1] = f2bf(vg.y); og.h[2] = f2bf(vg.z); og.h[3] = f2bf(vg.w);
        ou.h[0] = f2bf(vu.x); ou.h[1] = f2bf(vu.y); ou.h[2] = f2bf(vu.z); ou.h[3] = f2bf(vu.w);
        *reinterpret_cast<uint2*>(lG + row * 64 + pc) = og.w;
        *reinterpret_cast<uint2*>(lU + row * 64 + pc) = ou.w;
      }
    }
    asm volatile("s_waitcnt vmcnt(0)" ::: "memory");
    __syncthreads();

#pragma unroll
    for (int kk = 0; kk < 2; kk++) {
      int kbs = (((kk * 4 + (lane >> 4)) ^ (lane & 7))) * 8;  // swizzled read chunk
      short8 af[4];
#pragma unroll
      for (int m = 0; m < 4; m++)
        af[m] = *reinterpret_cast<const short8*>(pa[m] + ko + kk * 32);
#pragma unroll
      for (int n = 0; n < 4; n++) {
        int hr = wc * 64 + n * 16 + (lane & 15);
        short8 bg = *reinterpret_cast<const short8*>(lG + hr * 64 + kbs);
        short8 bu = *reinterpret_cast<const short8*>(lU + hr * 64 + kbs);
#pragma unroll
        for (int m = 0; m < 4; m++) {
          accG[m][n] = __builtin_amdgcn_mfma_f32_16x16x32_bf16(af[m], bg, accG[m][n], 0, 0, 0);
          accU[m][n] = __builtin_amdgcn_mfma_f32_16x16x32_bf16(af[m], bu, accU[m][n], 0, 0, 0);
        }
      }
    }
  }

  int rsub = (lane >> 4) * 4, csub = lane & 15;
#pragma unroll
  for (int m = 0; m < 4; m++) {
#pragma unroll
    for (int i = 0; i < 4; i++) {
      int row = wr * 64 + m * 16 + rsub + i;
      int gm = mt * 128 + row;
      if (gm < Me) {
        size_t rb = (size_t)(base + gm) * HDIM + nt * 128;
#pragma unroll
        for (int n = 0; n < 4; n++) {
          float hg = accG[m][n][i];
          float hu = accU[m][n][i];
          float a = 0.5f * hg * (1.f + erff(hg * 0.70710678118f)) * hu;
          Abuf[rb + wc * 64 + n * 16 + csub] = f2bf(a);
        }
      }
    }
  }
}

// ---------------- pass 2: Y = A Wd^T, scatter to out ----------------
template<bool WB>
__global__ __launch_bounds__(256, 2) void pass2_kernel(
    const u16* __restrict__ Abuf, const void* __restrict__ WDall,
    const void* __restrict__ SD, const int* __restrict__ tok,
    const float* __restrict__ wtl, const int* __restrict__ cnt,
    const int* __restrict__ offs, float* __restrict__ out, int e0, int mode) {
  int e = e0 + blockIdx.z;
  int mt = blockIdx.y;
  int nt = blockIdx.x;
  int Me = cnt[e];
  if (mt * 128 >= Me) return;
  int base = offs[e];
  size_t wst = (size_t)HDIM * DDIM;

  __shared__ u16 lA[128 * 64];
  __shared__ u16 lB[128 * 64];

  int tid = threadIdx.x, lane = tid & 63, wv = tid >> 6;
  int wr = wv >> 1, wc = wv & 1;
  int swsrc = ((lane & 7) ^ (lane >> 3)) * 8;

  const u16* ga[4];
#pragma unroll
  for (int q = 0; q < 4; q++) {
    int r = (wv * 4 + q) * 8 + (lane >> 3);
    int slot = base + mt * 128 + r;  // overrun rows only feed discarded output rows
    ga[q] = Abuf + (size_t)slot * HDIM + swsrc;
  }

  const u16* gb[4];
  const float* pd0 = nullptr;
  if constexpr (WB) {
    const u16* D = (e == 8) ? (const u16*)SD : (const u16*)WDall + (size_t)e * wst;
#pragma unroll
    for (int q = 0; q < 4; q++) {
      int r = (wv * 4 + q) * 8 + (lane >> 3);
      gb[q] = D + (size_t)(nt * 128 + r) * HDIM + swsrc;
    }
  } else {
    const float* D = (e == 8) ? (const float*)SD : (const float*)WDall + (size_t)e * wst;
    int r0 = wv * 32 + (lane >> 4);
    int c0 = (lane & 15) * 4;
    pd0 = D + (size_t)(nt * 128 + r0) * HDIM + c0;
  }

  f32x4 acc[4][4] = {};

  for (int kt = 0; kt < HDIM / 64; kt++) {
    __syncthreads();
    int ko = kt * 64;
#pragma unroll
    for (int q = 0; q < 4; q++) {
      int ldsoff = (wv * 4 + q) * 512;
      __builtin_amdgcn_global_load_lds(
          (const __attribute__((address_space(1))) unsigned int*)(ga[q] + ko),
          (__attribute__((address_space(3))) unsigned int*)(lA + ldsoff), 16, 0, 0);
      if constexpr (WB) {
        __builtin_amdgcn_global_load_lds(
            (const __attribute__((address_space(1))) unsigned int*)(gb[q] + ko),
            (__attribute__((address_space(3))) unsigned int*)(lB + ldsoff), 16, 0, 0);
      }
    }
    if constexpr (!WB) {
      int r0 = wv * 32 + (lane >> 4);
      int c0 = (lane & 15) * 4;
      int chunk = c0 >> 3, win = c0 & 7;
#pragma unroll
      for (int q = 0; q < 8; q++) {
        int row = r0 + q * 4;
        int pc = (((chunk ^ (row & 7)) << 3) | win);
        float4 vd = *reinterpret_cast<const float4*>(pd0 + ko + q * 4 * HDIM);
        union { u16 h[4]; uint2 w; } od;
        od.h[0] = f2bf(vd.x); od.h[1] = f2bf(vd.y); od.h[2] = f2bf(vd.z); od.h[3] = f2bf(vd.w);
        *reinterpret_cast<uint2*>(lB + row * 64 + pc) = od.w;
      }
    }
    asm volatile("s_waitcnt vmcnt(0)" ::: "memory");
    __syncthreads();

#pragma unroll
    for (int kk = 0; kk < 2; kk++) {
      int kbs = (((kk * 4 + (lane >> 4)) ^ (lane & 7))) * 8;
      short8 af[4];
#pragma unroll
      for (int m = 0; m < 4; m++) {
        int row = wr * 64 + m * 16 + (lane & 15);
        af[m] = *reinterpret_cast<const short8*>(lA + row * 64 + kbs);
      }
#pragma unroll
      for (int n = 0; n < 4; n++) {
        int dr = wc * 64 + n * 16 + (lane & 15);
        short8 bd = *reinterpret_cast<const short8*>(lB + dr * 64 + kbs);
#pragma unroll
        for (int m = 0; m < 4; m++) {
          acc[m][n] = __builtin_amdgcn_mfma_f32_16x16x32_bf16(af[m], bd, acc[m][n], 0, 0, 0);
        }
      }
    }
  }

  int rsub = (lane >> 4) * 4, csub = lane & 15;
#pragma unroll
  for (int m = 0; m < 4; m++) {
#pragma unroll
    for (int i = 0; i < 4; i++) {
      int row = wr * 64 + m * 16 + rsub + i;
      int gm = mt * 128 + row;
      if (gm < Me) {
        int t = tok[e * NTOK + gm];
        float w = mode ? wtl[e * NTOK + gm] : 1.f;
        size_t ob = (size_t)t * DDIM + nt * 128;
#pragma unroll
        for (int n = 0; n < 4; n++) {
          float v = w * acc[m][n][i];
          int c = wc * 64 + n * 16 + csub;
          if (mode) atomicAdd(&out[ob + c], v);
          else out[ob + c] = v;
        }
      }
    }
  }
}

// ---------------- host launcher ----------------
extern "C" void kernel_launch(void* const* d_in, const int* in_sizes, int n_in,
                              void* d_out, int out_size, void* d_ws, size_t ws_size,
                              hipStream_t stream) {
  const float* x  = (const float*)d_in[0];
  const float* gw = (const float*)d_in[1];
  const float* wg = (const float*)d_in[2];
  const float* wu = (const float*)d_in[3];
  const float* wd = (const float*)d_in[4];
  const float* sg = (const float*)d_in[5];
  const float* su = (const float*)d_in[6];
  const float* sd = (const float*)d_in[7];
  float* out = (float*)d_out;

  bool tierA = ws_size >= 470000000ULL;
  bool tierB = !tierA && ws_size >= 315000000ULL;
  bool batched = tierA || tierB;
  bool wcvt = tierA;

  char* ws = (char*)d_ws;
  size_t o = 0;
  auto alloc = [&](size_t bytes) -> void* {
    void* p = ws + o;
    o = (o + bytes + 255) & ~(size_t)255;
    return p;
  };
  u16* xbf = (u16*)alloc((size_t)NTOK * DDIM * 2);
  u16 *wgbf = nullptr, *wubf = nullptr, *wdbf = nullptr;
  u16 *sgbf = nullptr, *subf = nullptr, *sdbf = nullptr;
  if (wcvt) {
    wgbf = (u16*)alloc((size_t)NE * HDIM * DDIM * 2);
    wubf = (u16*)alloc((size_t)NE * HDIM * DDIM * 2);
    wdbf = (u16*)alloc((size_t)NE * DDIM * HDIM * 2);
    sgbf = (u16*)alloc((size_t)HDIM * DDIM * 2);
    subf = (u16*)alloc((size_t)HDIM * DDIM * 2);
    sdbf = (u16*)alloc((size_t)DDIM * HDIM * 2);
  }
  size_t abuf_rows = batched ? ((size_t)3 * NTOK + 128) : ((size_t)NTOK + 128);
  u16* Abuf = (u16*)alloc(abuf_rows * HDIM * 2);
  int*   tok  = (int*)alloc((size_t)NEX * NTOK * 4);
  float* wtl  = (float*)alloc((size_t)NEX * NTOK * 4);
  int*   cnt  = (int*)alloc(64);
  int*   offs = (int*)alloc(64);
  float* Pacc = (float*)alloc(64);
  float* fcnt = (float*)alloc(64);

  init_kernel<<<1, 64, 0, stream>>>(cnt, Pacc, fcnt);

  CvtArgs ca;
  long long sizes4[7];
  int nsrc;
  ca.src[0] = x; ca.dst[0] = xbf;
  sizes4[0] = (long long)NTOK * DDIM / 4;
  if (wcvt) {
    ca.src[1] = wg; ca.dst[1] = wgbf; sizes4[1] = (long long)NE * HDIM * DDIM / 4;
    ca.src[2] = wu; ca.dst[2] = wubf; sizes4[2] = (long long)NE * HDIM * DDIM / 4;
    ca.src[3] = wd; ca.dst[3] = wdbf; sizes4[3] = (long long)NE * DDIM * HDIM / 4;
    ca.src[4] = sg; ca.dst[4] = sgbf; sizes4[4] = (long long)HDIM * DDIM / 4;
    ca.src[5] = su; ca.dst[5] = subf; sizes4[5] = (long long)HDIM * DDIM / 4;
    ca.src[6] = sd; ca.dst[6] = sdbf; sizes4[6] = (long long)DDIM * HDIM / 4;
    nsrc = 7;
  } else {
    nsrc = 1;
  }
  ca.cum[0] = 0;
  for (int i = 0; i < 7; i++)
    ca.cum[i + 1] = ca.cum[i] + (i < nsrc ? sizes4[i] : 0);
  convert_kernel<<<4096, 256, 0, stream>>>(ca);

  router_kernel<<<NTOK / 16, 256, 0, stream>>>(x, gw, tok, wtl, cnt, Pacc, fcnt);
  finalize_router<<<1, 64, 0, stream>>>(cnt, offs, Pacc, fcnt,
                                        out + (out_size - 1), batched ? 1 : 0);

  const void *WG, *WU, *WD, *SG, *SU, *SD;
  if (wcvt) { WG = wgbf; WU = wubf; WD = wdbf; SG = sgbf; SU = subf; SD = sdbf; }
  else      { WG = wg;   WU = wu;   WD = wd;   SG = sg;   SU = su;   SD = sd;  }

  if (batched) {
    if (wcvt) {
      pass1_kernel<true><<<dim3(HDIM / 128, NTOK / 128, NEX), 256, 0, stream>>>(
          xbf, WG, WU, SG, SU, tok, cnt, offs, Abuf, 0);
      pass2_kernel<true><<<dim3(DDIM / 128, NTOK / 128, 1), 256, 0, stream>>>(
          Abuf, WD, SD, tok, wtl, cnt, offs, out, 8, 0);
      pass2_kernel<true><<<dim3(DDIM / 128, NTOK / 128, NE), 256, 0, stream>>>(
          Abuf, WD, SD, tok, wtl, cnt, offs, out, 0, 1);
    } else {
      pass1_kernel<false><<<dim3(HDIM / 128, NTOK / 128, NEX), 256, 0, stream>>>(
          xbf, WG, WU, SG, SU, tok, cnt, offs, Abuf, 0);
      pass2_kernel<false><<<dim3(DDIM / 128, NTOK / 128, 1), 256, 0, stream>>>(
          Abuf, WD, SD, tok, wtl, cnt, offs, out, 8, 0);
      pass2_kernel<false><<<dim3(DDIM / 128, NTOK / 128, NE), 256, 0, stream>>>(
          Abuf, WD, SD, tok, wtl, cnt, offs, out, 0, 1);
    }
  } else {
    for (int k = 0; k < NEX; k++) {
      int e = (k == 0) ? 8 : (k - 1);
      pass1_kernel<false><<<dim3(HDIM / 128, NTOK / 128, 1), 256, 0, stream>>>(
          xbf, WG, WU, SG, SU, tok, cnt, offs, Abuf, e);
      pass2_kernel<false><<<dim3(DDIM / 128, NTOK / 128, 1), 256, 0, stream>>>(
          Abuf, WD, SD, tok, wtl, cnt, offs, out, e, (e == 8) ? 0 : 1);
    }
  }
}